// Round 2
// baseline (599.463 us; speedup 1.0000x reference)
//
#include <hip/hip_runtime.h>
#include <math.h>

#define NB      65536
#define TSTEPS  100
#define DDIM    16
#define HID     64
#define ROWS    128     // batch rows per block (= threads per block)
#define LDSROW  36      // LDS row stride in floats: 32 data + 4 pad (keeps 16B align, spreads banks)

__device__ __forceinline__ float fsigmoid(float x) {
    return 1.0f / (1.0f + __expf(-x));
}
// NaN-safe tanh: exp of a non-positive argument only.
__device__ __forceinline__ float ftanh(float x) {
    float a = fabsf(x);
    float t = __expf(-2.0f * a);
    return copysignf((1.0f - t) / (1.0f + t), x);
}

__global__ void __launch_bounds__(128, 1)
lstm_mlp_fused(const float* __restrict__ X,
               const float* __restrict__ W_ih,
               const float* __restrict__ W_hh,
               const float* __restrict__ b_ih,
               const float* __restrict__ b_hh,
               const float* __restrict__ W1,
               const float* __restrict__ b1,
               const float* __restrict__ W2,
               const float* __restrict__ b2,
               const float* __restrict__ W3,
               const float* __restrict__ b3,
               float* __restrict__ out)
{
    // Static LDS total: 25600 + 36864 + 256 + 256 + 32 = 63008 B (<64KB static limit,
    // and 2 blocks/CU fit in 160KB).
    __shared__ __align__(16) float sW1T[TSTEPS * HID];     // W1 transposed: row t = 64 contiguous floats
    __shared__ __align__(16) float sX[2][ROWS * LDSROW];   // double-buffered X chunk (2 timesteps)
    __shared__ __align__(16) float sWih[4 * DDIM];
    __shared__ __align__(16) float sB1[HID];
    __shared__ float sMisc[8];                             // [0:4) b_ih+b_hh, [4:8) W_hh

    const int tid = threadIdx.x;

    // Transpose W1 (HID,T) -> (T,HID) so the scan reads one contiguous 64-float row per t.
    for (int i = tid; i < TSTEPS * HID; i += 128) {
        int j = i / TSTEPS;
        int t = i - j * TSTEPS;
        sW1T[t * HID + j] = W1[i];
    }
    if (tid < 4 * DDIM) sWih[tid] = W_ih[tid];
    if (tid < HID)      sB1[tid]  = b1[tid];
    if (tid < 4) { sMisc[tid] = b_ih[tid] + b_hh[tid]; sMisc[4 + tid] = W_hh[tid]; }

    const int row0 = blockIdx.x * ROWS;
    // X as float4: each row is 400 float4s; chunk ch = float4 cols [8ch, 8ch+8).
    const float4* __restrict__ xg = reinterpret_cast<const float4*>(X) + (size_t)row0 * 400;
    const int srow = tid >> 3;   // 0..15: row-within-group for staging
    const int scol = tid & 7;    // 0..7:  float4 col for staging (lanes 0..7 contiguous -> coalesced)

    // ---- stage chunk 0 into buffer 0 ----
    float4 st[8];
    #pragma unroll
    for (int it = 0; it < 8; ++it)
        st[it] = xg[(size_t)(it * 16 + srow) * 400 + scol];
    #pragma unroll
    for (int it = 0; it < 8; ++it)
        *reinterpret_cast<float4*>(&sX[0][(it * 16 + srow) * LDSROW + scol * 4]) = st[it];
    __syncthreads();

    // Per-lane register copies (LDS reads guarantee VGPR residency; ~230 VGPRs total, fits 1 wave/SIMD).
    float wih[64];
    #pragma unroll
    for (int q = 0; q < 16; ++q) {
        float4 v = *reinterpret_cast<const float4*>(&sWih[4 * q]);
        wih[4*q] = v.x; wih[4*q+1] = v.y; wih[4*q+2] = v.z; wih[4*q+3] = v.w;
    }
    const float gb0 = sMisc[0], gb1 = sMisc[1], gb2 = sMisc[2], gb3 = sMisc[3];
    const float wh0 = sMisc[4], wh1 = sMisc[5], wh2 = sMisc[6], wh3 = sMisc[7];

    float y1[HID];
    #pragma unroll
    for (int q = 0; q < 16; ++q) {
        float4 v = *reinterpret_cast<const float4*>(&sB1[4 * q]);
        y1[4*q] = v.x; y1[4*q+1] = v.y; y1[4*q+2] = v.z; y1[4*q+3] = v.w;
    }

    float h = 0.0f, c = 0.0f;

    for (int ch = 0; ch < 50; ++ch) {
        // Prefetch next chunk (coalesced, in flight across this chunk's compute).
        if (ch < 49) {
            #pragma unroll
            for (int it = 0; it < 8; ++it)
                st[it] = xg[(size_t)(it * 16 + srow) * 400 + (ch + 1) * 8 + scol];
        }

        // Read own row's 32 floats (2 timesteps) from LDS.
        // Bank quad = 4*((tid+q)&7): uniform over all 32 banks for the wave.
        float xr[32];
        const float* mysX = &sX[ch & 1][tid * LDSROW];
        #pragma unroll
        for (int q = 0; q < 8; ++q) {
            float4 v = *reinterpret_cast<const float4*>(&mysX[4 * q]);
            xr[4*q] = v.x; xr[4*q+1] = v.y; xr[4*q+2] = v.z; xr[4*q+3] = v.w;
        }

        // Two LSTM steps, y1 fused.
        #pragma unroll
        for (int s = 0; s < 2; ++s) {
            float g0 = fmaf(h, wh0, gb0);
            float g1 = fmaf(h, wh1, gb1);
            float g2 = fmaf(h, wh2, gb2);
            float g3 = fmaf(h, wh3, gb3);
            #pragma unroll
            for (int d = 0; d < 16; ++d) {
                float xv = xr[s * 16 + d];
                g0 = fmaf(xv, wih[d],      g0);
                g1 = fmaf(xv, wih[16 + d], g1);
                g2 = fmaf(xv, wih[32 + d], g2);
                g3 = fmaf(xv, wih[48 + d], g3);
            }
            float ig = fsigmoid(g0);
            float fg = fsigmoid(g1);
            float gg = ftanh(g2);
            float og = fsigmoid(g3);
            c = fmaf(fg, c, ig * gg);
            h = og * ftanh(c);
            float rh = fmaxf(h, 0.0f);
            const float* w1row = &sW1T[(2 * ch + s) * HID];   // broadcast read
            #pragma unroll
            for (int q = 0; q < 16; ++q) {
                float4 w = *reinterpret_cast<const float4*>(&w1row[4 * q]);
                y1[4*q]   = fmaf(rh, w.x, y1[4*q]);
                y1[4*q+1] = fmaf(rh, w.y, y1[4*q+1]);
                y1[4*q+2] = fmaf(rh, w.z, y1[4*q+2]);
                y1[4*q+3] = fmaf(rh, w.w, y1[4*q+3]);
            }
        }

        // Write next chunk into the other buffer (safe: its readers all passed the
        // previous barrier), then one barrier publishes it.
        if (ch < 49) {
            float* dst = &sX[(ch + 1) & 1][0];
            #pragma unroll
            for (int it = 0; it < 8; ++it)
                *reinterpret_cast<float4*>(&dst[(it * 16 + srow) * LDSROW + scol * 4]) = st[it];
        }
        __syncthreads();
    }

    // ---- MLP tail (per-lane; W2/W3/b2/b3 via uniform global loads -> scalar cache) ----
    #pragma unroll
    for (int j = 0; j < HID; ++j) y1[j] = fmaxf(y1[j], 0.0f);

    float o0 = b3[0], o1 = b3[1];
    for (int k = 0; k < HID; ++k) {
        float acc = b2[k];
        const float4* w2row = reinterpret_cast<const float4*>(W2 + k * HID);
        #pragma unroll
        for (int q = 0; q < 16; ++q) {
            float4 w = w2row[q];
            acc = fmaf(y1[4*q],   w.x, acc);
            acc = fmaf(y1[4*q+1], w.y, acc);
            acc = fmaf(y1[4*q+2], w.z, acc);
            acc = fmaf(y1[4*q+3], w.w, acc);
        }
        acc = fmaxf(acc, 0.0f);
        o0 = fmaf(acc, W3[k], o0);
        o1 = fmaf(acc, W3[HID + k], o1);
    }

    float m = fmaxf(o0, o1);
    float lse = m + __logf(__expf(o0 - m) + __expf(o1 - m));
    reinterpret_cast<float2*>(out)[row0 + tid] = make_float2(o0 - lse, o1 - lse);
}

extern "C" void kernel_launch(void* const* d_in, const int* in_sizes, int n_in,
                              void* d_out, int out_size, void* d_ws, size_t ws_size,
                              hipStream_t stream) {
    const float* X    = (const float*)d_in[0];
    const float* W_ih = (const float*)d_in[1];
    const float* W_hh = (const float*)d_in[2];
    const float* b_ih = (const float*)d_in[3];
    const float* b_hh = (const float*)d_in[4];
    const float* W1   = (const float*)d_in[5];
    const float* b1   = (const float*)d_in[6];
    const float* W2   = (const float*)d_in[7];
    const float* b2   = (const float*)d_in[8];
    const float* W3   = (const float*)d_in[9];
    const float* b3   = (const float*)d_in[10];
    float* out = (float*)d_out;

    lstm_mlp_fused<<<NB / ROWS, ROWS, 0, stream>>>(
        X, W_ih, W_hh, b_ih, b_hh, W1, b1, W2, b2, W3, b3, out);
}